// Round 14
// baseline (246.385 us; speedup 1.0000x reference)
//
#include <hip/hip_runtime.h>
#include <cfloat>
#include <cstdint>
#include <cstddef>

// Problem constants
#define N_B 2          // batch
#define C3v 256        // channels lv3
#define Gg 48          // query grid = 48x48
#define Lq 2304        // Gg*Gg
#define NCHUNK 64
#define CHUNK 36       // Lq / NCHUNK
#define OXS 2305       // (Lq+1): x-tap stride in flat C0/Tm
#define OYS 110640     // 48*(Lq+1): y-tap stride (multiple of 4 -> aligned)
#define TGUARD 110848  // guard floats around Tm (>= OYS + 2308, 256-aligned)

typedef __attribute__((ext_vector_type(8))) short short8;
typedef __attribute__((ext_vector_type(4))) float f32x4;
typedef unsigned short u16;

__device__ inline float bf2f(u16 h) {
    return __builtin_bit_cast(float, (unsigned)h << 16);
}
__device__ inline u16 f2bf_rne(float v) {
    unsigned u = __builtin_bit_cast(unsigned, v);
    unsigned r = (u + 0x7FFFu + ((u >> 16) & 1u)) >> 16;
    return (u16)r;
}

// ============================= small kernels =============================

__global__ void sqnorm_kernel(const float* __restrict__ refsr, const float* __restrict__ lr,
                              float* __restrict__ sref, float* __restrict__ sq) {
    int which = blockIdx.z, n = blockIdx.y;
    int p = blockIdx.x * 256 + threadIdx.x;
    const float* src = (which ? lr : refsr) + (size_t)n * C3v * Lq + p;
    float s0 = 0.f, s1 = 0.f, s2 = 0.f, s3 = 0.f;   // 4 chains for ILP
#pragma unroll 4
    for (int c = 0; c < C3v; c += 4) {
        float v0 = src[(size_t)c * Lq];
        float v1 = src[(size_t)(c + 1) * Lq];
        float v2 = src[(size_t)(c + 2) * Lq];
        float v3 = src[(size_t)(c + 3) * Lq];
        s0 = fmaf(v0, v0, s0); s1 = fmaf(v1, v1, s1);
        s2 = fmaf(v2, v2, s2); s3 = fmaf(v3, v3, s3);
    }
    (which ? sq : sref)[n * Lq + p] = (s0 + s1) + (s2 + s3);
}

__global__ void invnorm_kernel(const float* __restrict__ sref, const float* __restrict__ sq,
                               float* __restrict__ invK, float* __restrict__ invQ) {
    int which = blockIdx.z, n = blockIdx.y;
    int p = blockIdx.x * 256 + threadIdx.x;
    int py = p / Gg, px = p - (p / Gg) * Gg;
    const float* S = (which ? sq : sref) + n * Lq;
    float s = 0.f;
    for (int oy = -1; oy <= 1; ++oy) {
        int y = py + oy; if ((unsigned)y >= Gg) continue;
        for (int ox = -1; ox <= 1; ++ox) {
            int x = px + ox; if ((unsigned)x >= Gg) continue;
            s += S[y * Gg + x];
        }
    }
    (which ? invQ : invK)[n * Lq + p] = 1.0f / fmaxf(sqrtf(s), 1e-12f);
}

// =================== fp32 -> (bf16 hi, bf16 lo) transpose =================
// 64p x 16c tile, float4 reads, uint2 packed writes (4 ch/thread).
__global__ __launch_bounds__(256) void conv_split(const float* __restrict__ X, const float* __restrict__ Y,
                                                  u16* __restrict__ XH, u16* __restrict__ XL,
                                                  u16* __restrict__ YH, u16* __restrict__ YL) {
    __shared__ float tsm[16][65];
    int z = blockIdx.z; int which = z & 1, n = z >> 1;
    const float* src = (which ? Y : X) + (size_t)n * C3v * Lq;
    u16* H = (which ? YH : XH) + (size_t)n * Lq * C3v;
    u16* L = (which ? YL : XL) + (size_t)n * Lq * C3v;
    int p0 = blockIdx.x * 64, c0 = blockIdx.y * 16;
    int cc = threadIdx.x >> 4, p4 = (threadIdx.x & 15) << 2;
    float4 v4 = *(const float4*)&src[(size_t)(c0 + cc) * Lq + p0 + p4];
    tsm[cc][p4] = v4.x; tsm[cc][p4 + 1] = v4.y;
    tsm[cc][p4 + 2] = v4.z; tsm[cc][p4 + 3] = v4.w;
    __syncthreads();
    int pw = threadIdx.x >> 2, cq = (threadIdx.x & 3) << 2;
    unsigned hp[2], lp[2];
#pragma unroll
    for (int j = 0; j < 2; ++j) {
        u16 h0, h1, l0, l1;
        {
            float v = tsm[cq + 2 * j][pw];
            h0 = f2bf_rne(v); l0 = f2bf_rne(v - bf2f(h0));
        }
        {
            float v = tsm[cq + 2 * j + 1][pw];
            h1 = f2bf_rne(v); l1 = f2bf_rne(v - bf2f(h1));
        }
        hp[j] = (unsigned)h0 | ((unsigned)h1 << 16);
        lp[j] = (unsigned)l0 | ((unsigned)l1 << 16);
    }
    size_t o = (size_t)(p0 + pw) * C3v + c0 + cq;      // multiple of 4 -> 8B aligned
    *(uint2*)&H[o] = make_uint2(hp[0], hp[1]);
    *(uint2*)&L[o] = make_uint2(lp[0], lp[1]);
}

// ========================= C0 GEMM via split-bf16 MFMA ====================
__global__ __launch_bounds__(256) void gemm_mfma(const u16* __restrict__ XH_, const u16* __restrict__ XL_,
                                                 const u16* __restrict__ YH_, const u16* __restrict__ YL_,
                                                 float* __restrict__ C0) {
    int n = blockIdx.z;
    int r0 = blockIdx.y * 128, q0 = blockIdx.x * 128;
    const u16* XH = XH_ + (size_t)n * Lq * C3v;
    const u16* XL = XL_ + (size_t)n * Lq * C3v;
    const u16* YH = YH_ + (size_t)n * Lq * C3v;
    const u16* YL = YL_ + (size_t)n * Lq * C3v;
    float* Cb = C0 + (size_t)n * Lq * Lq;
    __shared__ __align__(16) u16 lds[16384];   // AH|AL|BH|BL, 4096 u16 each
    u16* AH = lds; u16* AL = lds + 4096; u16* BH = lds + 8192; u16* BL = lds + 12288;
    int t = threadIdx.x;
    int srow = t >> 1, sh = t & 1;             // staging: row, 16-ch half
    const u16* gXH = XH + (size_t)(r0 + srow) * C3v + sh * 16;
    const u16* gXL = XL + (size_t)(r0 + srow) * C3v + sh * 16;
    const u16* gYH = YH + (size_t)(q0 + srow) * C3v + sh * 16;
    const u16* gYL = YL + (size_t)(q0 + srow) * C3v + sh * 16;
    int sidx = (sh * 2) * 1024 + srow * 8;     // kg slots 2h, 2h+1
    int lane = t & 63, w = t >> 6;
    int wr = (w >> 1) * 64, wq = (w & 1) * 64;
    int fr = lane & 15, kg = lane >> 4;
    int ridx = kg * 1024 + fr * 8;
    f32x4 acc[4][4];
#pragma unroll
    for (int i = 0; i < 4; ++i)
#pragma unroll
        for (int j = 0; j < 4; ++j) acc[i][j] = (f32x4){0.f, 0.f, 0.f, 0.f};

    uint4 pXH0 = *(const uint4*)(gXH), pXH1 = *(const uint4*)(gXH + 8);
    uint4 pXL0 = *(const uint4*)(gXL), pXL1 = *(const uint4*)(gXL + 8);
    uint4 pYH0 = *(const uint4*)(gYH), pYH1 = *(const uint4*)(gYH + 8);
    uint4 pYL0 = *(const uint4*)(gYL), pYL1 = *(const uint4*)(gYL + 8);

    for (int c0 = 0; c0 < C3v; c0 += 32) {
        __syncthreads();
        *(uint4*)&AH[sidx] = pXH0; *(uint4*)&AH[sidx + 1024] = pXH1;
        *(uint4*)&AL[sidx] = pXL0; *(uint4*)&AL[sidx + 1024] = pXL1;
        *(uint4*)&BH[sidx] = pYH0; *(uint4*)&BH[sidx + 1024] = pYH1;
        *(uint4*)&BL[sidx] = pYL0; *(uint4*)&BL[sidx + 1024] = pYL1;
        __syncthreads();
        if (c0 + 32 < C3v) {
            pXH0 = *(const uint4*)(gXH + c0 + 32); pXH1 = *(const uint4*)(gXH + c0 + 40);
            pXL0 = *(const uint4*)(gXL + c0 + 32); pXL1 = *(const uint4*)(gXL + c0 + 40);
            pYH0 = *(const uint4*)(gYH + c0 + 32); pYH1 = *(const uint4*)(gYH + c0 + 40);
            pYL0 = *(const uint4*)(gYL + c0 + 32); pYL1 = *(const uint4*)(gYL + c0 + 40);
        }
        short8 ah[4], al[4];
#pragma unroll
        for (int fi = 0; fi < 4; ++fi) {
            ah[fi] = *(const short8*)&AH[ridx + (wr + fi * 16) * 8];
            al[fi] = *(const short8*)&AL[ridx + (wr + fi * 16) * 8];
        }
#pragma unroll
        for (int fj = 0; fj < 4; ++fj) {
            short8 bh = *(const short8*)&BH[ridx + (wq + fj * 16) * 8];
            short8 bl = *(const short8*)&BL[ridx + (wq + fj * 16) * 8];
#pragma unroll
            for (int fi = 0; fi < 4; ++fi) {
                acc[fi][fj] = __builtin_amdgcn_mfma_f32_16x16x32_bf16(al[fi], bh, acc[fi][fj], 0, 0, 0);
                acc[fi][fj] = __builtin_amdgcn_mfma_f32_16x16x32_bf16(ah[fi], bl, acc[fi][fj], 0, 0, 0);
                acc[fi][fj] = __builtin_amdgcn_mfma_f32_16x16x32_bf16(ah[fi], bh, acc[fi][fj], 0, 0, 0);
            }
        }
    }
    int orow = (lane >> 4) * 4;                 // C/D: col=lane&15, row=(lane>>4)*4+j
#pragma unroll
    for (int fi = 0; fi < 4; ++fi)
#pragma unroll
        for (int fj = 0; fj < 4; ++fj)
#pragma unroll
            for (int j = 0; j < 4; ++j)
                Cb[(size_t)(r0 + wr + fi * 16 + orow + j) * Lq + q0 + wq + fj * 16 + fr] = acc[fi][fj][j];
}

// ==================== separable stencil: y-pass (aligned) =================
// Tm[p] = mT*C0[p-OYS] + C0[p] + mB*C0[p+OYS]; all taps aligned float4.
__global__ __launch_bounds__(256) void stencil_y(const float* __restrict__ C0, float* __restrict__ Tm) {
    size_t idx = ((size_t)blockIdx.x * 256 + threadIdx.x) * 4;
    int col = (int)(idx % Lq);
    int rowg = (int)(idx / Lq);                 // n*2304 + r
    int r = rowg - (rowg >= Lq ? Lq : 0);
    int ry = r / Gg;
    int qy = col / Gg;                          // uniform across the 4 elems
    bool mT = (ry >= 1) & (qy >= 1);
    bool mB = (ry <= Gg - 2) & (qy <= Gg - 2);
    float4 top = *(const float4*)&C0[idx - OYS];
    float4 mid = *(const float4*)&C0[idx];
    float4 bot = *(const float4*)&C0[idx + OYS];
    float ov[4];
#pragma unroll
    for (int e = 0; e < 4; ++e) {
        float tv = ((const float*)&top)[e];
        float mv = ((const float*)&mid)[e];
        float bv = ((const float*)&bot)[e];
        float v = (mT ? tv : 0.f) + mv;
        v += (mB ? bv : 0.f);
        ov[e] = v;
    }
    *(float4*)&Tm[idx] = make_float4(ov[0], ov[1], ov[2], ov[3]);
}

// ======================= top-3 (2-stage over r) ==========================
// x-pass + running top-3: 3 loads per r at +-OXS (q-coalesced), x-masks.
__global__ __launch_bounds__(256) void topk_stage1_sep(const float* __restrict__ Tm, const float* __restrict__ invK,
                                                       float* __restrict__ ptv, int* __restrict__ pti) {
    int n = blockIdx.z;
    int ck = blockIdx.y;
    int q = blockIdx.x * 256 + threadIdx.x;
    int qx = q - (q / Gg) * Gg;
    bool qvx0 = qx >= 1, qvx2 = qx <= Gg - 2;
    const float* Tb = Tm + (size_t)n * Lq * Lq + q;
    const float* iK = invK + n * Lq;
    float t0 = -FLT_MAX, t1 = -FLT_MAX, t2 = -FLT_MAX;
    int i0 = -1, i1 = -1, i2 = -1;
    int r_end = ck * CHUNK + CHUNK;
#pragma unroll 4
    for (int r = ck * CHUNK; r < r_end; ++r) {
        int rx = r - (r / Gg) * Gg;
        size_t p = (size_t)r * Lq;
        float lf = Tb[p - OXS];                 // guard-band safe
        float mf = Tb[p];
        float rf = Tb[p + OXS];
        bool mL = (rx >= 1) & qvx0;
        bool mR = (rx <= Gg - 2) & qvx2;
        float raw = (mL ? lf : 0.f) + mf;
        raw += (mR ? rf : 0.f);
        float v = raw * iK[r];
        if (v > t0)      { t2 = t1; i2 = i1; t1 = t0; i1 = i0; t0 = v; i0 = r; }
        else if (v > t1) { t2 = t1; i2 = i1; t1 = v;  i1 = r; }
        else if (v > t2) { t2 = v;  i2 = r; }
    }
    size_t off = ((size_t)(n * NCHUNK + ck) * Lq + q) * 3;
    ptv[off] = t0; ptv[off + 1] = t1; ptv[off + 2] = t2;
    pti[off] = i0; pti[off + 1] = i1; pti[off + 2] = i2;
}

// fallback (no-ws path): 9-tap direct on C0
__global__ __launch_bounds__(256) void topk_stage1_direct(const float* __restrict__ C0, const float* __restrict__ invK,
                                                          float* __restrict__ ptv, int* __restrict__ pti) {
    int n = blockIdx.z;
    int ck = blockIdx.y;
    int q = blockIdx.x * 256 + threadIdx.x;
    int qy = q / Gg, qx = q - (q / Gg) * Gg;
    bool qvy0 = qy >= 1, qvy2 = qy <= Gg - 2;
    bool qvx0 = qx >= 1, qvx2 = qx <= Gg - 2;
    const float* Cb = C0 + (size_t)n * Lq * Lq + q;
    const float* iK = invK + n * Lq;
    float t0 = -FLT_MAX, t1 = -FLT_MAX, t2 = -FLT_MAX;
    int i0 = -1, i1 = -1, i2 = -1;
    int r_end = ck * CHUNK + CHUNK;
#pragma unroll 2
    for (int r = ck * CHUNK; r < r_end; ++r) {
        int ry = r / Gg, rx = r - (r / Gg) * Gg;
        const float* base = Cb + (size_t)r * Lq;
        float raw = 0.f;
#pragma unroll
        for (int oy = -1; oy <= 1; ++oy) {
            bool my = ((unsigned)(ry + oy) < Gg) && (oy < 0 ? qvy0 : (oy > 0 ? qvy2 : true));
#pragma unroll
            for (int ox = -1; ox <= 1; ++ox) {
                bool m = my && ((unsigned)(rx + ox) < Gg) && (ox < 0 ? qvx0 : (ox > 0 ? qvx2 : true));
                ptrdiff_t o = (ptrdiff_t)(oy * Gg + ox) * (Lq + 1);
                float ld = base[o];
                raw += m ? ld : 0.f;
            }
        }
        float v = raw * iK[r];
        if (v > t0)      { t2 = t1; i2 = i1; t1 = t0; i1 = i0; t0 = v; i0 = r; }
        else if (v > t1) { t2 = t1; i2 = i1; t1 = v;  i1 = r; }
        else if (v > t2) { t2 = v;  i2 = r; }
    }
    size_t off = ((size_t)(n * NCHUNK + ck) * Lq + q) * 3;
    ptv[off] = t0; ptv[off + 1] = t1; ptv[off + 2] = t2;
    pti[off] = i0; pti[off + 1] = i1; pti[off + 2] = i2;
}

// stage2: 4-way parallel chunk merge per q (64 q x 4 threads per block).
__global__ __launch_bounds__(256) void topk_stage2(const float* __restrict__ ptv, const int* __restrict__ pti,
                                                   const float* __restrict__ invQ, int* __restrict__ hard,
                                                   float* __restrict__ Sout) {
    __shared__ float sv[64][4][3];
    __shared__ int   si[64][4][3];
    int ql = threadIdx.x & 63, j = threadIdx.x >> 6;
    int g = blockIdx.x * 64 + ql;
    int n = g / Lq, q = g - n * Lq;
    float t0 = -FLT_MAX, t1 = -FLT_MAX, t2 = -FLT_MAX;
    int i0 = -1, i1 = -1, i2 = -1;
    int ck0 = j * (NCHUNK / 4);
    for (int ck = ck0; ck < ck0 + NCHUNK / 4; ++ck) {
        size_t off = ((size_t)(n * NCHUNK + ck) * Lq + q) * 3;
#pragma unroll
        for (int m = 0; m < 3; ++m) {
            float v = ptv[off + m]; int idx = pti[off + m];
            if (v > t0)      { t2 = t1; i2 = i1; t1 = t0; i1 = i0; t0 = v; i0 = idx; }
            else if (v > t1) { t2 = t1; i2 = i1; t1 = v;  i1 = idx; }
            else if (v > t2) { t2 = v;  i2 = idx; }
        }
    }
    sv[ql][j][0] = t0; sv[ql][j][1] = t1; sv[ql][j][2] = t2;
    si[ql][j][0] = i0; si[ql][j][1] = i1; si[ql][j][2] = i2;
    __syncthreads();
    if (j == 0) {
        t0 = t1 = t2 = -FLT_MAX; i0 = i1 = i2 = -1;
#pragma unroll
        for (int jj = 0; jj < 4; ++jj)
#pragma unroll
            for (int m = 0; m < 3; ++m) {
                float v = sv[ql][jj][m]; int idx = si[ql][jj][m];
                if (v > t0)      { t2 = t1; i2 = i1; t1 = t0; i1 = i0; t0 = v; i0 = idx; }
                else if (v > t1) { t2 = t1; i2 = i1; t1 = v;  i1 = idx; }
                else if (v > t2) { t2 = v;  i2 = idx; }
            }
        float iq = invQ[g];
        Sout[0 * (N_B * Lq) + g] = t0 * iq;
        Sout[1 * (N_B * Lq) + g] = t1 * iq;
        Sout[2 * (N_B * Lq) + g] = t2 * iq;
        hard[(n * 3 + 0) * Lq + q] = i0;
        hard[(n * 3 + 1) * Lq + q] = i1;
        hard[(n * 3 + 2) * Lq + q] = i2;
    }
}

// ==================== NCHW fp32 -> NHWC bf16 transpose ====================
__global__ void nchw_to_nhwc_bf16(const float* __restrict__ in, u16* __restrict__ out,
                                  int C, int H, int W) {
    __shared__ float t[16][17];
    int bz = blockIdx.z; int n = bz / H; int y = bz - n * H;
    int x0 = blockIdx.x * 16, c0 = blockIdx.y * 16;
    int tx = threadIdx.x & 15, ty = threadIdx.x >> 4;
    t[ty][tx] = in[(((size_t)n * C + c0 + ty) * H + y) * W + x0 + tx];
    __syncthreads();
    out[(((size_t)n * H + y) * W + x0 + ty) * C + c0 + tx] = f2bf_rne(t[tx][ty]);
}

// ========================= transfer (gather+fold) ========================
// uint2 channel-QUAD gathers (4 ch / 8B load), 4 cells/thread preserved
// (the invariant whose violation sank r8). Blocks cover 16 cells; grid.x 3.
// Per-output add order (oa asc, ob asc) unchanged -> bit-identical.

__global__ __launch_bounds__(256) void t3_kernel(const int* __restrict__ hard, const u16* __restrict__ img_,
                                                 float* __restrict__ out) {
    int i = blockIdx.z >> 1, n = blockIdx.z & 1;
    int u = blockIdx.y;
    int grp = threadIdx.x >> 6;                // 4-cell group (0..3)
    int wb = blockIdx.x * 16 + grp * 4;
    int c4 = threadIdx.x & 63;                 // channel quad: 4c4..4c4+3
    const int* hb = hard + (size_t)(n * 3 + i) * Lq;
    const u16* img = img_ + (size_t)n * Lq * C3v;
    int cyc = 3 - (u == 0) - (u == Gg - 1);
    int rxA[3][6], spA[3][6];
    bool svA[3][6];
#pragma unroll
    for (int oa = 0; oa < 3; ++oa) {
        int gy = u - (oa - 1);
        bool gyv = (unsigned)gy < Gg;
#pragma unroll
        for (int x = 0; x < 6; ++x) {
            int gx = wb - 1 + x;
            bool gv = gyv & ((unsigned)gx < Gg);
            int r = hb[(gv ? gy : 0) * Gg + (gv ? gx : 0)];
            int ry = r / Gg, rx = r - (r / Gg) * Gg;
            int syb = ry + (oa - 1);
            bool sval = gv & ((unsigned)syb < Gg);
            rxA[oa][x] = rx;
            spA[oa][x] = (sval ? syb : 0) * Gg;
            svA[oa][x] = sval;
        }
    }
    float az[4][4];                            // [ch][cell]
#pragma unroll
    for (int k = 0; k < 4; ++k) {
        int w = wb + k;
        int cxc = 3 - (w == 0) - (w == Gg - 1);
        float a0 = 0.f, a1 = 0.f, a2 = 0.f, a3 = 0.f;
#pragma unroll
        for (int oa = 0; oa < 3; ++oa)
#pragma unroll
            for (int ob = 0; ob < 3; ++ob) {
                int x = k + 2 - ob;
                int sxb = rxA[oa][x] + (ob - 1);
                bool sv = svA[oa][x] & ((unsigned)sxb < Gg);
                uint2 pv = *(const uint2*)&img[((size_t)(spA[oa][x] + (sv ? sxb : 0))) * C3v + 4 * c4];
                float l0 = bf2f((u16)(pv.x & 0xFFFF)), l1 = bf2f((u16)(pv.x >> 16));
                float l2 = bf2f((u16)(pv.y & 0xFFFF)), l3 = bf2f((u16)(pv.y >> 16));
                a0 += sv ? l0 : 0.f; a1 += sv ? l1 : 0.f;
                a2 += sv ? l2 : 0.f; a3 += sv ? l3 : 0.f;
            }
        float d = (float)(cyc * cxc);
        az[0][k] = a0 / d; az[1][k] = a1 / d; az[2][k] = a2 / d; az[3][k] = a3 / d;
    }
    size_t base = (((size_t)(i * N_B + n) * C3v + 4 * c4) * Lq) + u * Gg + wb;
#pragma unroll
    for (int z = 0; z < 4; ++z)
        *(float4*)&out[base + (size_t)z * Lq] = make_float4(az[z][0], az[z][1], az[z][2], az[z][3]);
}

__global__ __launch_bounds__(256) void t2_kernel(const int* __restrict__ hard, const u16* __restrict__ img_,
                                                 float* __restrict__ out) {
    const int C = 128, Him = 96;
    int i = blockIdx.z >> 1, n = blockIdx.z & 1;
    int u = blockIdx.y;
    int grp = threadIdx.x >> 6;                // 4-cell group (0..3)
    int wb = blockIdx.x * 16 + grp * 4;
    int c4 = threadIdx.x & 31;                 // channel quad: 4c4..4c4+3
    int v = (threadIdx.x >> 5) & 1;
    const int* hb = hard + (size_t)(n * 3 + i) * Lq;
    const u16* img = img_ + (size_t)n * Him * Him * C;
    int cyc = 3 - (u == 0) - (u == Gg - 1);
    int rxA[3][6], syA[3][6];
    bool svA[3][6];
#pragma unroll
    for (int oa = 0; oa < 3; ++oa) {
        int gy = u - (oa - 1);
        bool gyv = (unsigned)gy < Gg;
#pragma unroll
        for (int x = 0; x < 6; ++x) {
            int gx = wb - 1 + x;
            bool gv = gyv & ((unsigned)gx < Gg);
            int r = hb[(gv ? gy : 0) * Gg + (gv ? gx : 0)];
            int ry = r / Gg, rx = r - (r / Gg) * Gg;
            int syb = ry + (oa - 1);
            bool sval = gv & ((unsigned)syb < Gg);
            rxA[oa][x] = rx;
            syA[oa][x] = 2 * (sval ? syb : 0) + v;
            svA[oa][x] = sval;
        }
    }
    size_t hw = (size_t)Him * Him;
#pragma unroll
    for (int k = 0; k < 4; ++k) {
        int w = wb + k;
        int cxc = 3 - (w == 0) - (w == Gg - 1);
        float p0c[4] = {0.f, 0.f, 0.f, 0.f};   // px0, ch 0..3
        float p1c[4] = {0.f, 0.f, 0.f, 0.f};   // px1, ch 0..3
#pragma unroll
        for (int oa = 0; oa < 3; ++oa)
#pragma unroll
            for (int ob = 0; ob < 3; ++ob) {
                int x = k + 2 - ob;
                int sxb = rxA[oa][x] + (ob - 1);
                bool sv = svA[oa][x] & ((unsigned)sxb < Gg);
                int sxc = sv ? sxb : 0;
                const u16* row = &img[((size_t)syA[oa][x] * Him + 2 * sxc) * C + 4 * c4];
                uint2 q0 = *(const uint2*)&row[0];
                uint2 q1 = *(const uint2*)&row[C];
                float v00 = bf2f((u16)(q0.x & 0xFFFF)), v01 = bf2f((u16)(q0.x >> 16));
                float v02 = bf2f((u16)(q0.y & 0xFFFF)), v03 = bf2f((u16)(q0.y >> 16));
                float v10 = bf2f((u16)(q1.x & 0xFFFF)), v11 = bf2f((u16)(q1.x >> 16));
                float v12 = bf2f((u16)(q1.y & 0xFFFF)), v13 = bf2f((u16)(q1.y >> 16));
                p0c[0] += sv ? v00 : 0.f; p0c[1] += sv ? v01 : 0.f;
                p0c[2] += sv ? v02 : 0.f; p0c[3] += sv ? v03 : 0.f;
                p1c[0] += sv ? v10 : 0.f; p1c[1] += sv ? v11 : 0.f;
                p1c[2] += sv ? v12 : 0.f; p1c[3] += sv ? v13 : 0.f;
            }
        float d = (float)(cyc * cxc);
        size_t baseL = (((size_t)(i * N_B + n) * C + 4 * c4) * hw) + (size_t)(2 * u + v) * Him + 2 * w;
#pragma unroll
        for (int z = 0; z < 4; ++z)
            *(float2*)&out[baseL + (size_t)z * hw] = make_float2(p0c[z] / d, p1c[z] / d);
    }
}

template <bool NHWC>
__global__ __launch_bounds__(256) void t1_kernel(const int* __restrict__ hard, const void* __restrict__ img_,
                                                 float* __restrict__ out) {
    const int C = 64, Him = 192;
    int i = blockIdx.z >> 1, n = blockIdx.z & 1;
    int u = blockIdx.y;
    int grp = threadIdx.x >> 6;                // 4-cell group (0..3)
    int wb = blockIdx.x * 16 + grp * 4;
    int c4 = threadIdx.x & 15;                 // channel quad: 4c4..4c4+3
    int v = (threadIdx.x >> 4) & 3;
    const int* hb = hard + (size_t)(n * 3 + i) * Lq;
    const u16* img = (const u16*)img_ + (size_t)n * Him * Him * C;  // NHWC bf16
    const float* imgf = (const float*)img_;                          // NCHW fp32 (fallback)
    int cyc = 3 - (u == 0) - (u == Gg - 1);
    int rxA[3][6], syA[3][6];
    bool svA[3][6];
#pragma unroll
    for (int oa = 0; oa < 3; ++oa) {
        int gy = u - (oa - 1);
        bool gyv = (unsigned)gy < Gg;
#pragma unroll
        for (int x = 0; x < 6; ++x) {
            int gx = wb - 1 + x;
            bool gv = gyv & ((unsigned)gx < Gg);
            int r = hb[(gv ? gy : 0) * Gg + (gv ? gx : 0)];
            int ry = r / Gg, rx = r - (r / Gg) * Gg;
            int syb = ry + (oa - 1);
            bool sval = gv & ((unsigned)syb < Gg);
            rxA[oa][x] = rx;
            syA[oa][x] = 4 * (sval ? syb : 0) + v;
            svA[oa][x] = sval;
        }
    }
    size_t hw = (size_t)Him * Him;
#pragma unroll
    for (int k = 0; k < 4; ++k) {
        int w = wb + k;
        int cxc = 3 - (w == 0) - (w == Gg - 1);
        float zc[4][4];                        // [ch][px]
#pragma unroll
        for (int z = 0; z < 4; ++z)
#pragma unroll
            for (int p = 0; p < 4; ++p) zc[z][p] = 0.f;
#pragma unroll
        for (int oa = 0; oa < 3; ++oa)
#pragma unroll
            for (int ob = 0; ob < 3; ++ob) {
                int x = k + 2 - ob;
                int sxb = rxA[oa][x] + (ob - 1);
                bool sv = svA[oa][x] & ((unsigned)sxb < Gg);
                int sxc = sv ? sxb : 0;
                int sy = syA[oa][x], sx = 4 * sxc;
                if (NHWC) {
                    const u16* row = &img[((size_t)sy * Him + sx) * C + 4 * c4];
#pragma unroll
                    for (int p = 0; p < 4; ++p) {
                        uint2 q = *(const uint2*)&row[p * C];
                        float l0 = bf2f((u16)(q.x & 0xFFFF)), l1 = bf2f((u16)(q.x >> 16));
                        float l2 = bf2f((u16)(q.y & 0xFFFF)), l3 = bf2f((u16)(q.y >> 16));
                        zc[0][p] += sv ? l0 : 0.f;
                        zc[1][p] += sv ? l1 : 0.f;
                        zc[2][p] += sv ? l2 : 0.f;
                        zc[3][p] += sv ? l3 : 0.f;
                    }
                } else {
#pragma unroll
                    for (int z = 0; z < 4; ++z) {
                        const float* row = &imgf[(((size_t)(n * C + 4 * c4 + z)) * Him + sy) * Him + sx];
#pragma unroll
                        for (int p = 0; p < 4; ++p) {
                            float lv = row[p];
                            zc[z][p] += sv ? lv : 0.f;
                        }
                    }
                }
            }
        float d = (float)(cyc * cxc);
        size_t baseL = (((size_t)(i * N_B + n) * C + 4 * c4) * hw) + (size_t)(4 * u + v) * Him + 4 * w;
#pragma unroll
        for (int z = 0; z < 4; ++z)
            *(float4*)&out[baseL + (size_t)z * hw] =
                make_float4(zc[z][0] / d, zc[z][1] / d, zc[z][2] / d, zc[z][3] / d);
    }
}

// ============================== launcher =================================

extern "C" void kernel_launch(void* const* d_in, const int* in_sizes, int n_in,
                              void* d_out, int out_size, void* d_ws, size_t ws_size,
                              hipStream_t stream) {
    (void)in_sizes; (void)n_in; (void)out_size;
    const float* lr    = (const float*)d_in[0];
    const float* refsr = (const float*)d_in[1];
    const float* ref1  = (const float*)d_in[2];
    const float* ref2  = (const float*)d_in[3];
    const float* ref3  = (const float*)d_in[4];
    float* out = (float*)d_out;

    // output layout (floats): S | T3 | T2 | T1
    const size_t S_OFF  = 0;
    const size_t T3_OFF = 13824;
    const size_t T2_OFF = 3552768;
    const size_t T1_OFF = 10630656;

    // ws smalls
    float* wsf  = (float*)d_ws;
    float* sref = wsf;                       // 4608
    float* sq   = wsf + 4608;
    float* invK = wsf + 2 * 4608;
    float* invQ = wsf + 3 * 4608;
    int*   hard = (int*)(wsf + 4 * 4608);    // 13824 ints
    size_t small_elems = 4 * 4608 + 13824;
    size_t small_bytes = small_elems * 4;

    // top-k partials in d_out's T3 region (consumed by stage2 before t3 writes)
    float* ptv = out + T3_OFF;               // N_B*NCHUNK*Lq*3 floats
    int*   pti = (int*)(ptv + (size_t)N_B * NCHUNK * Lq * 3);

    // bf16 hi/lo transposed operands in d_out's T2 region (dead after gemm)
    u16* XHp = (u16*)(out + T2_OFF);
    u16* XLp = XHp + (size_t)N_B * Lq * C3v;
    u16* YHp = XLp + (size_t)N_B * Lq * C3v;
    u16* YLp = YHp + (size_t)N_B * Lq * C3v;

    // y-pass stencil buffer in d_out's T1 region (guarded; consumed by
    // stage1 before t1 writes)
    float* Tm = out + T1_OFF + TGUARD;

    // big region: guard | C0[2][2304][2304] | guard (reused for bf16 NHWC refs)
    const size_t GUARD = 120000;
    size_t big_off  = (small_bytes + 255) & ~(size_t)255;
    size_t big_need = (2 * (size_t)Lq * Lq + 2 * GUARD) * 4;
    bool primary = (ws_size >= big_off + big_need);
    float* big = primary ? (float*)((char*)d_ws + big_off) : (out + T1_OFF);
    float* C0    = big + GUARD;
    u16* nhwc3 = (u16*)big;
    u16* nhwc2 = nhwc3 + (size_t)N_B * Lq * C3v;
    u16* nhwc1 = nhwc2 + (size_t)N_B * 96 * 96 * 128;

    sqnorm_kernel <<<dim3(9, 2, 2),  256, 0, stream>>>(refsr, lr, sref, sq);
    invnorm_kernel<<<dim3(9, 2, 2),  256, 0, stream>>>(sref, sq, invK, invQ);
    conv_split    <<<dim3(36, 16, 4), 256, 0, stream>>>(refsr, lr, XHp, XLp, YHp, YLp);
    gemm_mfma     <<<dim3(18, 18, 2), 256, 0, stream>>>(XHp, XLp, YHp, YLp, C0);
    if (primary) {
        stencil_y       <<<dim3(10368), 256, 0, stream>>>(C0, Tm);
        topk_stage1_sep <<<dim3(9, NCHUNK, 2), 256, 0, stream>>>(Tm, invK, ptv, pti);
    } else {
        topk_stage1_direct<<<dim3(9, NCHUNK, 2), 256, 0, stream>>>(C0, invK, ptv, pti);
    }
    topk_stage2   <<<dim3(72), 256, 0, stream>>>(ptv, pti, invQ, hard, out + S_OFF);
    nchw_to_nhwc_bf16<<<dim3(3, 16, 2 * 48),  256, 0, stream>>>(ref3, nhwc3, 256, 48, 48);
    nchw_to_nhwc_bf16<<<dim3(6, 8,  2 * 96),  256, 0, stream>>>(ref2, nhwc2, 128, 96, 96);
    if (primary)
        nchw_to_nhwc_bf16<<<dim3(12, 4, 2 * 192), 256, 0, stream>>>(ref1, nhwc1, 64, 192, 192);
    t3_kernel<<<dim3(3, 48, 6), 256, 0, stream>>>(hard, nhwc3, out + T3_OFF);
    t2_kernel<<<dim3(3, 48, 6), 256, 0, stream>>>(hard, nhwc2, out + T2_OFF);
    if (primary) t1_kernel<true> <<<dim3(3, 48, 6), 256, 0, stream>>>(hard, nhwc1, out + T1_OFF);
    else         t1_kernel<false><<<dim3(3, 48, 6), 256, 0, stream>>>(hard, ref1, out + T1_OFF);
}

// Round 15
// 215.334 us; speedup vs baseline: 1.1442x; 1.1442x over previous
//
#include <hip/hip_runtime.h>
#include <cfloat>
#include <cstdint>
#include <cstddef>

// Problem constants
#define N_B 2          // batch
#define C3v 256        // channels lv3
#define Gg 48          // query grid = 48x48
#define Lq 2304        // Gg*Gg
#define NCHUNK 64
#define CHUNK 36       // Lq / NCHUNK
#define OXS 2305       // (Lq+1): x-tap stride in flat C0/Tm
#define OYS 110640     // 48*(Lq+1): y-tap stride (multiple of 4 -> aligned)
#define TGUARD 110848  // guard floats around Tm (>= OYS + 2308, 256-aligned)

typedef __attribute__((ext_vector_type(8))) short short8;
typedef __attribute__((ext_vector_type(4))) float f32x4;
typedef unsigned short u16;

__device__ inline float bf2f(u16 h) {
    return __builtin_bit_cast(float, (unsigned)h << 16);
}
__device__ inline u16 f2bf_rne(float v) {
    unsigned u = __builtin_bit_cast(unsigned, v);
    unsigned r = (u + 0x7FFFu + ((u >> 16) & 1u)) >> 16;
    return (u16)r;
}

// ============================= small kernels =============================

__global__ void sqnorm_kernel(const float* __restrict__ refsr, const float* __restrict__ lr,
                              float* __restrict__ sref, float* __restrict__ sq) {
    int which = blockIdx.z, n = blockIdx.y;
    int p = blockIdx.x * 256 + threadIdx.x;
    const float* src = (which ? lr : refsr) + (size_t)n * C3v * Lq + p;
    float s0 = 0.f, s1 = 0.f, s2 = 0.f, s3 = 0.f;   // 4 chains for ILP
#pragma unroll 4
    for (int c = 0; c < C3v; c += 4) {
        float v0 = src[(size_t)c * Lq];
        float v1 = src[(size_t)(c + 1) * Lq];
        float v2 = src[(size_t)(c + 2) * Lq];
        float v3 = src[(size_t)(c + 3) * Lq];
        s0 = fmaf(v0, v0, s0); s1 = fmaf(v1, v1, s1);
        s2 = fmaf(v2, v2, s2); s3 = fmaf(v3, v3, s3);
    }
    (which ? sq : sref)[n * Lq + p] = (s0 + s1) + (s2 + s3);
}

__global__ void invnorm_kernel(const float* __restrict__ sref, const float* __restrict__ sq,
                               float* __restrict__ invK, float* __restrict__ invQ) {
    int which = blockIdx.z, n = blockIdx.y;
    int p = blockIdx.x * 256 + threadIdx.x;
    int py = p / Gg, px = p - (p / Gg) * Gg;
    const float* S = (which ? sq : sref) + n * Lq;
    float s = 0.f;
    for (int oy = -1; oy <= 1; ++oy) {
        int y = py + oy; if ((unsigned)y >= Gg) continue;
        for (int ox = -1; ox <= 1; ++ox) {
            int x = px + ox; if ((unsigned)x >= Gg) continue;
            s += S[y * Gg + x];
        }
    }
    (which ? invQ : invK)[n * Lq + p] = 1.0f / fmaxf(sqrtf(s), 1e-12f);
}

// =================== fp32 -> (bf16 hi, bf16 lo) transpose =================
// 64p x 16c tile, float4 reads, uint2 packed writes (4 ch/thread).
__global__ __launch_bounds__(256) void conv_split(const float* __restrict__ X, const float* __restrict__ Y,
                                                  u16* __restrict__ XH, u16* __restrict__ XL,
                                                  u16* __restrict__ YH, u16* __restrict__ YL) {
    __shared__ float tsm[16][65];
    int z = blockIdx.z; int which = z & 1, n = z >> 1;
    const float* src = (which ? Y : X) + (size_t)n * C3v * Lq;
    u16* H = (which ? YH : XH) + (size_t)n * Lq * C3v;
    u16* L = (which ? YL : XL) + (size_t)n * Lq * C3v;
    int p0 = blockIdx.x * 64, c0 = blockIdx.y * 16;
    int cc = threadIdx.x >> 4, p4 = (threadIdx.x & 15) << 2;
    float4 v4 = *(const float4*)&src[(size_t)(c0 + cc) * Lq + p0 + p4];
    tsm[cc][p4] = v4.x; tsm[cc][p4 + 1] = v4.y;
    tsm[cc][p4 + 2] = v4.z; tsm[cc][p4 + 3] = v4.w;
    __syncthreads();
    int pw = threadIdx.x >> 2, cq = (threadIdx.x & 3) << 2;
    unsigned hp[2], lp[2];
#pragma unroll
    for (int j = 0; j < 2; ++j) {
        u16 h0, h1, l0, l1;
        {
            float v = tsm[cq + 2 * j][pw];
            h0 = f2bf_rne(v); l0 = f2bf_rne(v - bf2f(h0));
        }
        {
            float v = tsm[cq + 2 * j + 1][pw];
            h1 = f2bf_rne(v); l1 = f2bf_rne(v - bf2f(h1));
        }
        hp[j] = (unsigned)h0 | ((unsigned)h1 << 16);
        lp[j] = (unsigned)l0 | ((unsigned)l1 << 16);
    }
    size_t o = (size_t)(p0 + pw) * C3v + c0 + cq;      // multiple of 4 -> 8B aligned
    *(uint2*)&H[o] = make_uint2(hp[0], hp[1]);
    *(uint2*)&L[o] = make_uint2(lp[0], lp[1]);
}

// ========================= C0 GEMM via split-bf16 MFMA ====================
__global__ __launch_bounds__(256) void gemm_mfma(const u16* __restrict__ XH_, const u16* __restrict__ XL_,
                                                 const u16* __restrict__ YH_, const u16* __restrict__ YL_,
                                                 float* __restrict__ C0) {
    int n = blockIdx.z;
    int r0 = blockIdx.y * 128, q0 = blockIdx.x * 128;
    const u16* XH = XH_ + (size_t)n * Lq * C3v;
    const u16* XL = XL_ + (size_t)n * Lq * C3v;
    const u16* YH = YH_ + (size_t)n * Lq * C3v;
    const u16* YL = YL_ + (size_t)n * Lq * C3v;
    float* Cb = C0 + (size_t)n * Lq * Lq;
    __shared__ __align__(16) u16 lds[16384];   // AH|AL|BH|BL, 4096 u16 each
    u16* AH = lds; u16* AL = lds + 4096; u16* BH = lds + 8192; u16* BL = lds + 12288;
    int t = threadIdx.x;
    int srow = t >> 1, sh = t & 1;             // staging: row, 16-ch half
    const u16* gXH = XH + (size_t)(r0 + srow) * C3v + sh * 16;
    const u16* gXL = XL + (size_t)(r0 + srow) * C3v + sh * 16;
    const u16* gYH = YH + (size_t)(q0 + srow) * C3v + sh * 16;
    const u16* gYL = YL + (size_t)(q0 + srow) * C3v + sh * 16;
    int sidx = (sh * 2) * 1024 + srow * 8;     // kg slots 2h, 2h+1
    int lane = t & 63, w = t >> 6;
    int wr = (w >> 1) * 64, wq = (w & 1) * 64;
    int fr = lane & 15, kg = lane >> 4;
    int ridx = kg * 1024 + fr * 8;
    f32x4 acc[4][4];
#pragma unroll
    for (int i = 0; i < 4; ++i)
#pragma unroll
        for (int j = 0; j < 4; ++j) acc[i][j] = (f32x4){0.f, 0.f, 0.f, 0.f};

    uint4 pXH0 = *(const uint4*)(gXH), pXH1 = *(const uint4*)(gXH + 8);
    uint4 pXL0 = *(const uint4*)(gXL), pXL1 = *(const uint4*)(gXL + 8);
    uint4 pYH0 = *(const uint4*)(gYH), pYH1 = *(const uint4*)(gYH + 8);
    uint4 pYL0 = *(const uint4*)(gYL), pYL1 = *(const uint4*)(gYL + 8);

    for (int c0 = 0; c0 < C3v; c0 += 32) {
        __syncthreads();
        *(uint4*)&AH[sidx] = pXH0; *(uint4*)&AH[sidx + 1024] = pXH1;
        *(uint4*)&AL[sidx] = pXL0; *(uint4*)&AL[sidx + 1024] = pXL1;
        *(uint4*)&BH[sidx] = pYH0; *(uint4*)&BH[sidx + 1024] = pYH1;
        *(uint4*)&BL[sidx] = pYL0; *(uint4*)&BL[sidx + 1024] = pYL1;
        __syncthreads();
        if (c0 + 32 < C3v) {
            pXH0 = *(const uint4*)(gXH + c0 + 32); pXH1 = *(const uint4*)(gXH + c0 + 40);
            pXL0 = *(const uint4*)(gXL + c0 + 32); pXL1 = *(const uint4*)(gXL + c0 + 40);
            pYH0 = *(const uint4*)(gYH + c0 + 32); pYH1 = *(const uint4*)(gYH + c0 + 40);
            pYL0 = *(const uint4*)(gYL + c0 + 32); pYL1 = *(const uint4*)(gYL + c0 + 40);
        }
        short8 ah[4], al[4];
#pragma unroll
        for (int fi = 0; fi < 4; ++fi) {
            ah[fi] = *(const short8*)&AH[ridx + (wr + fi * 16) * 8];
            al[fi] = *(const short8*)&AL[ridx + (wr + fi * 16) * 8];
        }
#pragma unroll
        for (int fj = 0; fj < 4; ++fj) {
            short8 bh = *(const short8*)&BH[ridx + (wq + fj * 16) * 8];
            short8 bl = *(const short8*)&BL[ridx + (wq + fj * 16) * 8];
#pragma unroll
            for (int fi = 0; fi < 4; ++fi) {
                acc[fi][fj] = __builtin_amdgcn_mfma_f32_16x16x32_bf16(al[fi], bh, acc[fi][fj], 0, 0, 0);
                acc[fi][fj] = __builtin_amdgcn_mfma_f32_16x16x32_bf16(ah[fi], bl, acc[fi][fj], 0, 0, 0);
                acc[fi][fj] = __builtin_amdgcn_mfma_f32_16x16x32_bf16(ah[fi], bh, acc[fi][fj], 0, 0, 0);
            }
        }
    }
    int orow = (lane >> 4) * 4;                 // C/D: col=lane&15, row=(lane>>4)*4+j
#pragma unroll
    for (int fi = 0; fi < 4; ++fi)
#pragma unroll
        for (int fj = 0; fj < 4; ++fj)
#pragma unroll
            for (int j = 0; j < 4; ++j)
                Cb[(size_t)(r0 + wr + fi * 16 + orow + j) * Lq + q0 + wq + fj * 16 + fr] = acc[fi][fj][j];
}

// ==================== separable stencil: y-pass (aligned) =================
// Tm[p] = mT*C0[p-OYS] + C0[p] + mB*C0[p+OYS]; all taps aligned float4.
__global__ __launch_bounds__(256) void stencil_y(const float* __restrict__ C0, float* __restrict__ Tm) {
    size_t idx = ((size_t)blockIdx.x * 256 + threadIdx.x) * 4;
    int col = (int)(idx % Lq);
    int rowg = (int)(idx / Lq);                 // n*2304 + r
    int r = rowg - (rowg >= Lq ? Lq : 0);
    int ry = r / Gg;
    int qy = col / Gg;                          // uniform across the 4 elems
    bool mT = (ry >= 1) & (qy >= 1);
    bool mB = (ry <= Gg - 2) & (qy <= Gg - 2);
    float4 top = *(const float4*)&C0[idx - OYS];
    float4 mid = *(const float4*)&C0[idx];
    float4 bot = *(const float4*)&C0[idx + OYS];
    float ov[4];
#pragma unroll
    for (int e = 0; e < 4; ++e) {
        float tv = ((const float*)&top)[e];
        float mv = ((const float*)&mid)[e];
        float bv = ((const float*)&bot)[e];
        float v = (mT ? tv : 0.f) + mv;
        v += (mB ? bv : 0.f);
        ov[e] = v;
    }
    *(float4*)&Tm[idx] = make_float4(ov[0], ov[1], ov[2], ov[3]);
}

// ======================= top-3 (2-stage over r) ==========================
// x-pass + running top-3: 3 loads per r at +-OXS (q-coalesced), x-masks.
__global__ __launch_bounds__(256) void topk_stage1_sep(const float* __restrict__ Tm, const float* __restrict__ invK,
                                                       float* __restrict__ ptv, int* __restrict__ pti) {
    int n = blockIdx.z;
    int ck = blockIdx.y;
    int q = blockIdx.x * 256 + threadIdx.x;
    int qx = q - (q / Gg) * Gg;
    bool qvx0 = qx >= 1, qvx2 = qx <= Gg - 2;
    const float* Tb = Tm + (size_t)n * Lq * Lq + q;
    const float* iK = invK + n * Lq;
    float t0 = -FLT_MAX, t1 = -FLT_MAX, t2 = -FLT_MAX;
    int i0 = -1, i1 = -1, i2 = -1;
    int r_end = ck * CHUNK + CHUNK;
#pragma unroll 4
    for (int r = ck * CHUNK; r < r_end; ++r) {
        int rx = r - (r / Gg) * Gg;
        size_t p = (size_t)r * Lq;
        float lf = Tb[p - OXS];                 // guard-band safe
        float mf = Tb[p];
        float rf = Tb[p + OXS];
        bool mL = (rx >= 1) & qvx0;
        bool mR = (rx <= Gg - 2) & qvx2;
        float raw = (mL ? lf : 0.f) + mf;
        raw += (mR ? rf : 0.f);
        float v = raw * iK[r];
        if (v > t0)      { t2 = t1; i2 = i1; t1 = t0; i1 = i0; t0 = v; i0 = r; }
        else if (v > t1) { t2 = t1; i2 = i1; t1 = v;  i1 = r; }
        else if (v > t2) { t2 = v;  i2 = r; }
    }
    size_t off = ((size_t)(n * NCHUNK + ck) * Lq + q) * 3;
    ptv[off] = t0; ptv[off + 1] = t1; ptv[off + 2] = t2;
    pti[off] = i0; pti[off + 1] = i1; pti[off + 2] = i2;
}

// fallback (no-ws path): 9-tap direct on C0
__global__ __launch_bounds__(256) void topk_stage1_direct(const float* __restrict__ C0, const float* __restrict__ invK,
                                                          float* __restrict__ ptv, int* __restrict__ pti) {
    int n = blockIdx.z;
    int ck = blockIdx.y;
    int q = blockIdx.x * 256 + threadIdx.x;
    int qy = q / Gg, qx = q - (q / Gg) * Gg;
    bool qvy0 = qy >= 1, qvy2 = qy <= Gg - 2;
    bool qvx0 = qx >= 1, qvx2 = qx <= Gg - 2;
    const float* Cb = C0 + (size_t)n * Lq * Lq + q;
    const float* iK = invK + n * Lq;
    float t0 = -FLT_MAX, t1 = -FLT_MAX, t2 = -FLT_MAX;
    int i0 = -1, i1 = -1, i2 = -1;
    int r_end = ck * CHUNK + CHUNK;
#pragma unroll 2
    for (int r = ck * CHUNK; r < r_end; ++r) {
        int ry = r / Gg, rx = r - (r / Gg) * Gg;
        const float* base = Cb + (size_t)r * Lq;
        float raw = 0.f;
#pragma unroll
        for (int oy = -1; oy <= 1; ++oy) {
            bool my = ((unsigned)(ry + oy) < Gg) && (oy < 0 ? qvy0 : (oy > 0 ? qvy2 : true));
#pragma unroll
            for (int ox = -1; ox <= 1; ++ox) {
                bool m = my && ((unsigned)(rx + ox) < Gg) && (ox < 0 ? qvx0 : (ox > 0 ? qvx2 : true));
                ptrdiff_t o = (ptrdiff_t)(oy * Gg + ox) * (Lq + 1);
                float ld = base[o];
                raw += m ? ld : 0.f;
            }
        }
        float v = raw * iK[r];
        if (v > t0)      { t2 = t1; i2 = i1; t1 = t0; i1 = i0; t0 = v; i0 = r; }
        else if (v > t1) { t2 = t1; i2 = i1; t1 = v;  i1 = r; }
        else if (v > t2) { t2 = v;  i2 = r; }
    }
    size_t off = ((size_t)(n * NCHUNK + ck) * Lq + q) * 3;
    ptv[off] = t0; ptv[off + 1] = t1; ptv[off + 2] = t2;
    pti[off] = i0; pti[off + 1] = i1; pti[off + 2] = i2;
}

// stage2: 4-way parallel chunk merge per q (64 q x 4 threads per block).
__global__ __launch_bounds__(256) void topk_stage2(const float* __restrict__ ptv, const int* __restrict__ pti,
                                                   const float* __restrict__ invQ, int* __restrict__ hard,
                                                   float* __restrict__ Sout) {
    __shared__ float sv[64][4][3];
    __shared__ int   si[64][4][3];
    int ql = threadIdx.x & 63, j = threadIdx.x >> 6;
    int g = blockIdx.x * 64 + ql;
    int n = g / Lq, q = g - n * Lq;
    float t0 = -FLT_MAX, t1 = -FLT_MAX, t2 = -FLT_MAX;
    int i0 = -1, i1 = -1, i2 = -1;
    int ck0 = j * (NCHUNK / 4);
    for (int ck = ck0; ck < ck0 + NCHUNK / 4; ++ck) {
        size_t off = ((size_t)(n * NCHUNK + ck) * Lq + q) * 3;
#pragma unroll
        for (int m = 0; m < 3; ++m) {
            float v = ptv[off + m]; int idx = pti[off + m];
            if (v > t0)      { t2 = t1; i2 = i1; t1 = t0; i1 = i0; t0 = v; i0 = idx; }
            else if (v > t1) { t2 = t1; i2 = i1; t1 = v;  i1 = idx; }
            else if (v > t2) { t2 = v;  i2 = idx; }
        }
    }
    sv[ql][j][0] = t0; sv[ql][j][1] = t1; sv[ql][j][2] = t2;
    si[ql][j][0] = i0; si[ql][j][1] = i1; si[ql][j][2] = i2;
    __syncthreads();
    if (j == 0) {
        t0 = t1 = t2 = -FLT_MAX; i0 = i1 = i2 = -1;
#pragma unroll
        for (int jj = 0; jj < 4; ++jj)
#pragma unroll
            for (int m = 0; m < 3; ++m) {
                float v = sv[ql][jj][m]; int idx = si[ql][jj][m];
                if (v > t0)      { t2 = t1; i2 = i1; t1 = t0; i1 = i0; t0 = v; i0 = idx; }
                else if (v > t1) { t2 = t1; i2 = i1; t1 = v;  i1 = idx; }
                else if (v > t2) { t2 = v;  i2 = idx; }
            }
        float iq = invQ[g];
        Sout[0 * (N_B * Lq) + g] = t0 * iq;
        Sout[1 * (N_B * Lq) + g] = t1 * iq;
        Sout[2 * (N_B * Lq) + g] = t2 * iq;
        hard[(n * 3 + 0) * Lq + q] = i0;
        hard[(n * 3 + 1) * Lq + q] = i1;
        hard[(n * 3 + 2) * Lq + q] = i2;
    }
}

// ==================== NCHW fp32 -> NHWC bf16 transpose ====================
__global__ void nchw_to_nhwc_bf16(const float* __restrict__ in, u16* __restrict__ out,
                                  int C, int H, int W) {
    __shared__ float t[16][17];
    int bz = blockIdx.z; int n = bz / H; int y = bz - n * H;
    int x0 = blockIdx.x * 16, c0 = blockIdx.y * 16;
    int tx = threadIdx.x & 15, ty = threadIdx.x >> 4;
    t[ty][tx] = in[(((size_t)n * C + c0 + ty) * H + y) * W + x0 + tx];
    __syncthreads();
    out[(((size_t)n * H + y) * W + x0 + ty) * C + c0 + tx] = f2bf_rne(t[tx][ty]);
}

// ========================= transfer (gather+fold) ========================
// u32 channel-pair gathers, 4 cells/thread (validated r11/r12/r13 optimum;
// r14's channel-quad widening regressed -- grid too small, never retry).

__global__ __launch_bounds__(256) void t3_kernel(const int* __restrict__ hard, const u16* __restrict__ img_,
                                                 float* __restrict__ out) {
    int i = blockIdx.z >> 1, n = blockIdx.z & 1;
    int u = blockIdx.y;
    int half = threadIdx.x >> 7;               // which 4-cell group of the block's 8
    int wb = blockIdx.x * 8 + half * 4;
    int c2 = threadIdx.x & 127;                // channel pair: 2c2, 2c2+1
    const int* hb = hard + (size_t)(n * 3 + i) * Lq;
    const u16* img = img_ + (size_t)n * Lq * C3v;
    int cyc = 3 - (u == 0) - (u == Gg - 1);
    int rxA[3][6], spA[3][6];
    bool svA[3][6];
#pragma unroll
    for (int oa = 0; oa < 3; ++oa) {
        int gy = u - (oa - 1);
        bool gyv = (unsigned)gy < Gg;
#pragma unroll
        for (int x = 0; x < 6; ++x) {
            int gx = wb - 1 + x;
            bool gv = gyv & ((unsigned)gx < Gg);
            int r = hb[(gv ? gy : 0) * Gg + (gv ? gx : 0)];
            int ry = r / Gg, rx = r - (r / Gg) * Gg;
            int syb = ry + (oa - 1);
            bool sval = gv & ((unsigned)syb < Gg);
            rxA[oa][x] = rx;
            spA[oa][x] = (sval ? syb : 0) * Gg;
            svA[oa][x] = sval;
        }
    }
    float rlo[4], rhi[4];
#pragma unroll
    for (int k = 0; k < 4; ++k) {
        int w = wb + k;
        int cxc = 3 - (w == 0) - (w == Gg - 1);
        float alo = 0.f, ahi = 0.f;
#pragma unroll
        for (int oa = 0; oa < 3; ++oa)
#pragma unroll
            for (int ob = 0; ob < 3; ++ob) {
                int x = k + 2 - ob;
                int sxb = rxA[oa][x] + (ob - 1);
                bool sv = svA[oa][x] & ((unsigned)sxb < Gg);
                unsigned pv = *(const unsigned*)&img[((size_t)(spA[oa][x] + (sv ? sxb : 0))) * C3v + 2 * c2];
                float lo = bf2f((u16)(pv & 0xFFFF));
                float hi = bf2f((u16)(pv >> 16));
                alo += sv ? lo : 0.f;
                ahi += sv ? hi : 0.f;
            }
        float d = (float)(cyc * cxc);
        rlo[k] = alo / d; rhi[k] = ahi / d;
    }
    size_t base = (((size_t)(i * N_B + n) * C3v + 2 * c2) * Lq) + u * Gg + wb;
    *(float4*)&out[base]      = make_float4(rlo[0], rlo[1], rlo[2], rlo[3]);
    *(float4*)&out[base + Lq] = make_float4(rhi[0], rhi[1], rhi[2], rhi[3]);
}

__global__ __launch_bounds__(256) void t2_kernel(const int* __restrict__ hard, const u16* __restrict__ img_,
                                                 float* __restrict__ out) {
    const int C = 128, Him = 96;
    int i = blockIdx.z >> 1, n = blockIdx.z & 1;
    int u = blockIdx.y;
    int half = threadIdx.x >> 7;               // which 4-cell group of the block's 8
    int wb = blockIdx.x * 8 + half * 4;
    int c2 = threadIdx.x & 63;                 // channel pair: 2c2, 2c2+1
    int v = (threadIdx.x >> 6) & 1;
    const int* hb = hard + (size_t)(n * 3 + i) * Lq;
    const u16* img = img_ + (size_t)n * Him * Him * C;
    int cyc = 3 - (u == 0) - (u == Gg - 1);
    int rxA[3][6], syA[3][6];
    bool svA[3][6];
#pragma unroll
    for (int oa = 0; oa < 3; ++oa) {
        int gy = u - (oa - 1);
        bool gyv = (unsigned)gy < Gg;
#pragma unroll
        for (int x = 0; x < 6; ++x) {
            int gx = wb - 1 + x;
            bool gv = gyv & ((unsigned)gx < Gg);
            int r = hb[(gv ? gy : 0) * Gg + (gv ? gx : 0)];
            int ry = r / Gg, rx = r - (r / Gg) * Gg;
            int syb = ry + (oa - 1);
            bool sval = gv & ((unsigned)syb < Gg);
            rxA[oa][x] = rx;
            syA[oa][x] = 2 * (sval ? syb : 0) + v;
            svA[oa][x] = sval;
        }
    }
#pragma unroll
    for (int k = 0; k < 4; ++k) {
        int w = wb + k;
        int cxc = 3 - (w == 0) - (w == Gg - 1);
        float a0lo = 0.f, a0hi = 0.f, a1lo = 0.f, a1hi = 0.f;
#pragma unroll
        for (int oa = 0; oa < 3; ++oa)
#pragma unroll
            for (int ob = 0; ob < 3; ++ob) {
                int x = k + 2 - ob;
                int sxb = rxA[oa][x] + (ob - 1);
                bool sv = svA[oa][x] & ((unsigned)sxb < Gg);
                int sxc = sv ? sxb : 0;
                const u16* row = &img[((size_t)syA[oa][x] * Him + 2 * sxc) * C + 2 * c2];
                unsigned p0 = *(const unsigned*)&row[0];
                unsigned p1 = *(const unsigned*)&row[C];
                float v0lo = bf2f((u16)(p0 & 0xFFFF)), v0hi = bf2f((u16)(p0 >> 16));
                float v1lo = bf2f((u16)(p1 & 0xFFFF)), v1hi = bf2f((u16)(p1 >> 16));
                a0lo += sv ? v0lo : 0.f; a0hi += sv ? v0hi : 0.f;
                a1lo += sv ? v1lo : 0.f; a1hi += sv ? v1hi : 0.f;
            }
        float d = (float)(cyc * cxc);
        size_t hw = (size_t)Him * Him;
        size_t baseL = (((size_t)(i * N_B + n) * C + 2 * c2) * hw) + (size_t)(2 * u + v) * Him + 2 * w;
        *(float2*)&out[baseL]      = make_float2(a0lo / d, a1lo / d);
        *(float2*)&out[baseL + hw] = make_float2(a0hi / d, a1hi / d);
    }
}

template <bool NHWC>
__global__ __launch_bounds__(256) void t1_kernel(const int* __restrict__ hard, const void* __restrict__ img_,
                                                 float* __restrict__ out) {
    const int C = 64, Him = 192;
    int i = blockIdx.z >> 1, n = blockIdx.z & 1;
    int u = blockIdx.y;
    int half = threadIdx.x >> 7;               // which 4-cell group of the block's 8
    int wb = blockIdx.x * 8 + half * 4;
    int c2 = threadIdx.x & 31;                 // channel pair: channels 2c2, 2c2+1
    int v = (threadIdx.x >> 5) & 3;
    const int* hb = hard + (size_t)(n * 3 + i) * Lq;
    const u16* img = (const u16*)img_ + (size_t)n * Him * Him * C;  // NHWC bf16
    const float* imgf = (const float*)img_;                          // NCHW fp32 (fallback)
    int cyc = 3 - (u == 0) - (u == Gg - 1);
    int rxA[3][6], syA[3][6];
    bool svA[3][6];
#pragma unroll
    for (int oa = 0; oa < 3; ++oa) {
        int gy = u - (oa - 1);
        bool gyv = (unsigned)gy < Gg;
#pragma unroll
        for (int x = 0; x < 6; ++x) {
            int gx = wb - 1 + x;
            bool gv = gyv & ((unsigned)gx < Gg);
            int r = hb[(gv ? gy : 0) * Gg + (gv ? gx : 0)];
            int ry = r / Gg, rx = r - (r / Gg) * Gg;
            int syb = ry + (oa - 1);
            bool sval = gv & ((unsigned)syb < Gg);
            rxA[oa][x] = rx;
            syA[oa][x] = 4 * (sval ? syb : 0) + v;
            svA[oa][x] = sval;
        }
    }
    float4 flo[4], fhi[4];
#pragma unroll
    for (int k = 0; k < 4; ++k) {
        int w = wb + k;
        int cxc = 3 - (w == 0) - (w == Gg - 1);
        float zlo[4] = {0.f, 0.f, 0.f, 0.f};
        float zhi[4] = {0.f, 0.f, 0.f, 0.f};
#pragma unroll
        for (int oa = 0; oa < 3; ++oa)
#pragma unroll
            for (int ob = 0; ob < 3; ++ob) {
                int x = k + 2 - ob;
                int sxb = rxA[oa][x] + (ob - 1);
                bool sv = svA[oa][x] & ((unsigned)sxb < Gg);
                int sxc = sv ? sxb : 0;
                int sy = syA[oa][x], sx = 4 * sxc;
                if (NHWC) {
                    const u16* row = &img[((size_t)sy * Him + sx) * C + 2 * c2];
#pragma unroll
                    for (int z = 0; z < 4; ++z) {
                        unsigned pv = *(const unsigned*)&row[z * C];
                        float lo = bf2f((u16)(pv & 0xFFFF));
                        float hi = bf2f((u16)(pv >> 16));
                        zlo[z] += sv ? lo : 0.f;
                        zhi[z] += sv ? hi : 0.f;
                    }
                } else {
                    const float* rowL = &imgf[(((size_t)(n * C + 2 * c2)) * Him + sy) * Him + sx];
                    const float* rowH = rowL + (size_t)Him * Him;
#pragma unroll
                    for (int z = 0; z < 4; ++z) {
                        float lo = rowL[z], hi = rowH[z];
                        zlo[z] += sv ? lo : 0.f;
                        zhi[z] += sv ? hi : 0.f;
                    }
                }
            }
        float d = (float)(cyc * cxc);
        flo[k] = make_float4(zlo[0] / d, zlo[1] / d, zlo[2] / d, zlo[3] / d);
        fhi[k] = make_float4(zhi[0] / d, zhi[1] / d, zhi[2] / d, zhi[3] / d);
    }
    size_t hw = (size_t)Him * Him;
    size_t baseL = (((size_t)(i * N_B + n) * C + 2 * c2) * hw) + (size_t)(4 * u + v) * Him + 4 * wb;
#pragma unroll
    for (int k = 0; k < 4; ++k) {
        *(float4*)&out[baseL + 4 * k]      = flo[k];
        *(float4*)&out[baseL + hw + 4 * k] = fhi[k];
    }
}

// ============================== launcher =================================

extern "C" void kernel_launch(void* const* d_in, const int* in_sizes, int n_in,
                              void* d_out, int out_size, void* d_ws, size_t ws_size,
                              hipStream_t stream) {
    (void)in_sizes; (void)n_in; (void)out_size;
    const float* lr    = (const float*)d_in[0];
    const float* refsr = (const float*)d_in[1];
    const float* ref1  = (const float*)d_in[2];
    const float* ref2  = (const float*)d_in[3];
    const float* ref3  = (const float*)d_in[4];
    float* out = (float*)d_out;

    // output layout (floats): S | T3 | T2 | T1
    const size_t S_OFF  = 0;
    const size_t T3_OFF = 13824;
    const size_t T2_OFF = 3552768;
    const size_t T1_OFF = 10630656;

    // ws smalls
    float* wsf  = (float*)d_ws;
    float* sref = wsf;                       // 4608
    float* sq   = wsf + 4608;
    float* invK = wsf + 2 * 4608;
    float* invQ = wsf + 3 * 4608;
    int*   hard = (int*)(wsf + 4 * 4608);    // 13824 ints
    size_t small_elems = 4 * 4608 + 13824;
    size_t small_bytes = small_elems * 4;

    // top-k partials in d_out's T3 region (consumed by stage2 before t3 writes)
    float* ptv = out + T3_OFF;               // N_B*NCHUNK*Lq*3 floats
    int*   pti = (int*)(ptv + (size_t)N_B * NCHUNK * Lq * 3);

    // bf16 hi/lo transposed operands in d_out's T2 region (dead after gemm)
    u16* XHp = (u16*)(out + T2_OFF);
    u16* XLp = XHp + (size_t)N_B * Lq * C3v;
    u16* YHp = XLp + (size_t)N_B * Lq * C3v;
    u16* YLp = YHp + (size_t)N_B * Lq * C3v;

    // y-pass stencil buffer in d_out's T1 region (guarded; consumed by
    // stage1 before t1 writes)
    float* Tm = out + T1_OFF + TGUARD;

    // big region: guard | C0[2][2304][2304] | guard (reused for bf16 NHWC refs)
    const size_t GUARD = 120000;
    size_t big_off  = (small_bytes + 255) & ~(size_t)255;
    size_t big_need = (2 * (size_t)Lq * Lq + 2 * GUARD) * 4;
    bool primary = (ws_size >= big_off + big_need);
    float* big = primary ? (float*)((char*)d_ws + big_off) : (out + T1_OFF);
    float* C0    = big + GUARD;
    u16* nhwc3 = (u16*)big;
    u16* nhwc2 = nhwc3 + (size_t)N_B * Lq * C3v;
    u16* nhwc1 = nhwc2 + (size_t)N_B * 96 * 96 * 128;

    sqnorm_kernel <<<dim3(9, 2, 2),  256, 0, stream>>>(refsr, lr, sref, sq);
    invnorm_kernel<<<dim3(9, 2, 2),  256, 0, stream>>>(sref, sq, invK, invQ);
    conv_split    <<<dim3(36, 16, 4), 256, 0, stream>>>(refsr, lr, XHp, XLp, YHp, YLp);
    gemm_mfma     <<<dim3(18, 18, 2), 256, 0, stream>>>(XHp, XLp, YHp, YLp, C0);
    if (primary) {
        stencil_y       <<<dim3(10368), 256, 0, stream>>>(C0, Tm);
        topk_stage1_sep <<<dim3(9, NCHUNK, 2), 256, 0, stream>>>(Tm, invK, ptv, pti);
    } else {
        topk_stage1_direct<<<dim3(9, NCHUNK, 2), 256, 0, stream>>>(C0, invK, ptv, pti);
    }
    topk_stage2   <<<dim3(72), 256, 0, stream>>>(ptv, pti, invQ, hard, out + S_OFF);
    nchw_to_nhwc_bf16<<<dim3(3, 16, 2 * 48),  256, 0, stream>>>(ref3, nhwc3, 256, 48, 48);
    nchw_to_nhwc_bf16<<<dim3(6, 8,  2 * 96),  256, 0, stream>>>(ref2, nhwc2, 128, 96, 96);
    if (primary)
        nchw_to_nhwc_bf16<<<dim3(12, 4, 2 * 192), 256, 0, stream>>>(ref1, nhwc1, 64, 192, 192);
    t3_kernel<<<dim3(6, 48, 6), 256, 0, stream>>>(hard, nhwc3, out + T3_OFF);
    t2_kernel<<<dim3(6, 48, 6), 256, 0, stream>>>(hard, nhwc2, out + T2_OFF);
    if (primary) t1_kernel<true> <<<dim3(6, 48, 6), 256, 0, stream>>>(hard, nhwc1, out + T1_OFF);
    else         t1_kernel<false><<<dim3(6, 48, 6), 256, 0, stream>>>(hard, ref1, out + T1_OFF);
}